// Round 10
// baseline (1039.266 us; speedup 1.0000x reference)
//
#include <hip/hip_runtime.h>
#include <hip/hip_bf16.h>

#define NN 100000
#define NE 1600000
#define NB 64
#define DIN 78
#define DH 128
#define SD 768
#define FD 256
#define SCAN_NBLK 98   // ceil(NN/1024)

// 1/sqrt(1 + 1e-5)
#define BN_SCALE 0.9999950000374997f

typedef __attribute__((ext_vector_type(8))) short short8v;
typedef __attribute__((ext_vector_type(8))) unsigned short ushort8v;
typedef __attribute__((ext_vector_type(4))) float float4v;

__device__ __forceinline__ float bf2f(ushort u) {
    return __uint_as_float(((unsigned int)u) << 16);
}
__device__ __forceinline__ ushort f2bfu(float f) {
    __hip_bfloat16 h = __float2bfloat16(f);
    ushort u;
    __builtin_memcpy(&u, &h, 2);
    return u;
}

// ================= CSR build =================
__global__ void zero_counts(int* __restrict__ counts) {
    int i = blockIdx.x * 1024 + threadIdx.x;
    if (i < NN) counts[i] = 0;
}

__global__ void hist_kernel(const int* __restrict__ dst, int* __restrict__ counts) {
    int e = blockIdx.x * 256 + threadIdx.x;
    if (e < NE) atomicAdd(&counts[dst[e]], 1);
}

__global__ __launch_bounds__(1024) void scan1(const int* __restrict__ counts,
                                              int* __restrict__ excl,
                                              int* __restrict__ bsums) {
    __shared__ int tmp[1024];
    int tid = threadIdx.x;
    int i = blockIdx.x * 1024 + tid;
    int v = (i < NN) ? counts[i] : 0;
    tmp[tid] = v;
    __syncthreads();
#pragma unroll
    for (int off = 1; off < 1024; off <<= 1) {
        int t = (tid >= off) ? tmp[tid - off] : 0;
        __syncthreads();
        tmp[tid] += t;
        __syncthreads();
    }
    if (i < NN) excl[i] = tmp[tid] - v;
    if (tid == 1023) bsums[blockIdx.x] = tmp[1023];
}

__global__ __launch_bounds__(128) void scan2(int* __restrict__ bsums, int nb) {
    __shared__ int tmp[128];
    int tid = threadIdx.x;
    int v = (tid < nb) ? bsums[tid] : 0;
    tmp[tid] = v;
    __syncthreads();
#pragma unroll
    for (int off = 1; off < 128; off <<= 1) {
        int t = (tid >= off) ? tmp[tid - off] : 0;
        __syncthreads();
        tmp[tid] += t;
        __syncthreads();
    }
    if (tid < nb) bsums[tid] = tmp[tid] - v;
}

__global__ void scan3(const int* __restrict__ excl, const int* __restrict__ bsums,
                      int* __restrict__ offsets, int* __restrict__ cursor) {
    int i = blockIdx.x * 1024 + threadIdx.x;
    if (i < NN) {
        int v = excl[i] + bsums[blockIdx.x];
        offsets[i] = v;
        cursor[i] = v;
    }
}

// 8-pass dst-range-partitioned scatter (see R9 notes: read-side caching win).
__global__ __launch_bounds__(256) void scatter8(const int* __restrict__ src,
                                                const int* __restrict__ dst,
                                                int* __restrict__ cursor,
                                                int* __restrict__ eidx) {
    const int stride = 2048 * 256;
    int base = blockIdx.x * 256 + threadIdx.x;
#pragma unroll 1
    for (int p = 0; p < 8; ++p) {
        int dlo = p * (NN / 8);
        int dhi = (p == 7) ? NN : (p + 1) * (NN / 8);
#pragma unroll 1
        for (int e = base; e < NE; e += stride) {
            int d = dst[e];
            if (d >= dlo && d < dhi) {
                int q = atomicAdd(&cursor[d], 1);
                eidx[q] = src[e];
            }
        }
    }
}

// ================= x -> bf16 padded [NN][128] =================
__global__ __launch_bounds__(256) void xcast(const float* __restrict__ x,
                                             ushort* __restrict__ xb) {
    int node = blockIdx.x * 4 + (threadIdx.x >> 6);
    if (node >= NN) return;
    int lane = threadIdx.x & 63;
    int col = lane * 2;
    ushort2 o = make_ushort2(0, 0);
    if (lane < 39) {
        float2 v = *(const float2*)&x[(size_t)node * DIN + col];
        o.x = f2bfu(v.x);
        o.y = f2bfu(v.y);
    }
    *(ushort2*)&xb[(size_t)node * DH + col] = o;
}

// ================= weight prep: all 6 weights in one launch =================
// Wt layout per weight: [kt(4)][kc(4)][col(128)][j(8)]  (kk = kt*32+kc*8+j)
__global__ __launch_bounds__(256) void wprep6(
        const float* __restrict__ W0, const float* __restrict__ W1,
        const float* __restrict__ W2, const float* __restrict__ W3,
        const float* __restrict__ W4, const float* __restrict__ W5,
        ushort* __restrict__ Wt) {
    int w = blockIdx.x >> 3;                    // 0..5
    const float* W = (w == 0) ? W0 : (w == 1) ? W1 : (w == 2) ? W2
                   : (w == 3) ? W3 : (w == 4) ? W4 : W5;
    int KW = (w == 0) ? DIN : DH;
    int t = (blockIdx.x & 7) * 256 + threadIdx.x;   // 0..2047
    int kt = t >> 9, kc = (t >> 7) & 3, col = t & 127;
    ushort tmp[8];
#pragma unroll
    for (int j = 0; j < 8; ++j) {
        int kk = kt * 32 + kc * 8 + j;
        tmp[j] = (kk < KW) ? f2bfu(W[(size_t)kk * 128 + col]) : (ushort)0;
    }
    *(uint4*)&Wt[(size_t)w * 16384 + (size_t)t * 8] = *(uint4*)&tmp[0];
}

// ================= fused GIN layer =================
// Per block: 128 nodes. Phase 1: gather-agg into Afull LDS (bf16).
// Phase 2: Q = relu(A @ Wt1 + b1) -> back into Afull.
// Phase 3: R = relu((Q @ Wt2 + b2) * g*BN_SCALE + bb) -> global bf16.
__global__ __launch_bounds__(256) void layer_fused(
        const ushort* __restrict__ h, const int* __restrict__ off,
        const int* __restrict__ cnt, const int* __restrict__ eidx,
        const ushort* __restrict__ Wt1, const float* __restrict__ b1,
        const ushort* __restrict__ Wt2, const float* __restrict__ b2,
        const float* __restrict__ g, const float* __restrict__ bb,
        ushort* __restrict__ Cout, int nrows) {
    __shared__ ushort Afull[16][129][8];   // [chunk][row(+pad)][j] 33 KB
    __shared__ ushort Bst[4][128][8];      // per-kt B stage, 8 KB
    const int tid = threadIdx.x;
    const int wave = tid >> 6, lane = tid & 63;
    const int wm = wave >> 1, wn = wave & 1;
    const int lhi = lane >> 4;             // 0..3
    const int llo = lane & 15;
    const int r0 = blockIdx.x * 128;

    // ---- phase 1: gather-agg; quarter-wave (16 lanes x 16B) per neighbor ----
    {
        int q = lhi;                        // quarter id
        for (int i = 0; i < 32; ++i) {
            int row = wave * 32 + i;
            int node = r0 + row;
            float acc[8];
#pragma unroll
            for (int k = 0; k < 8; ++k) acc[k] = 0.f;
            if (node < nrows) {
                if (q == 0) {
                    ushort8v v = *(const ushort8v*)&h[(size_t)node * DH + llo * 8];
#pragma unroll
                    for (int k = 0; k < 8; ++k) acc[k] = bf2f(v[k]);
                }
                int start = off[node], deg = cnt[node];
                for (int base = 0; base < deg; base += 64) {
                    int rem = deg - base;
                    int m = rem < 64 ? rem : 64;
                    int ev = (lane < m) ? eidx[start + base + lane] : 0;
#pragma unroll 4
                    for (int j = q; j < m; j += 4) {
                        int s = __shfl(ev, j);
                        ushort8v v = *(const ushort8v*)&h[(size_t)s * DH + llo * 8];
#pragma unroll
                        for (int k = 0; k < 8; ++k) acc[k] += bf2f(v[k]);
                    }
                }
#pragma unroll
                for (int k = 0; k < 8; ++k) {
                    acc[k] += __shfl_xor(acc[k], 16);
                    acc[k] += __shfl_xor(acc[k], 32);
                }
            }
            if (q == 0) {
                ushort8v o;
#pragma unroll
                for (int k = 0; k < 8; ++k) o[k] = f2bfu(acc[k]);
                *(ushort8v*)&Afull[llo][row][0] = o;
            }
        }
    }
    __syncthreads();

    const uint4* W1v = (const uint4*)Wt1;
    const uint4* W2v = (const uint4*)Wt2;

    float4v acc[4][4];
#pragma unroll
    for (int i = 0; i < 4; ++i)
#pragma unroll
        for (int j = 0; j < 4; ++j) acc[i][j] = (float4v){0.f, 0.f, 0.f, 0.f};

    // ---- phase 2: GEMM1 ----
    for (int kt = 0; kt < 4; ++kt) {
#pragma unroll
        for (int p = tid; p < 512; p += 256)
            *(uint4*)&Bst[0][0][p * 8] = W1v[kt * 512 + p];
        __syncthreads();
        short8v av[4], bv[4];
#pragma unroll
        for (int s = 0; s < 4; ++s) {
            av[s] = *(const short8v*)&Afull[kt * 4 + lhi][wm * 64 + s * 16 + llo][0];
            bv[s] = *(const short8v*)&Bst[lhi][wn * 64 + s * 16 + llo][0];
        }
#pragma unroll
        for (int sm = 0; sm < 4; ++sm)
#pragma unroll
            for (int sn = 0; sn < 4; ++sn)
                acc[sm][sn] = __builtin_amdgcn_mfma_f32_16x16x32_bf16(
                    av[sm], bv[sn], acc[sm][sn], 0, 0, 0);
        __syncthreads();
    }

    // ---- epilogue1: relu(+b1) -> Afull (all reads of Afull are done) ----
#pragma unroll
    for (int sm = 0; sm < 4; ++sm)
#pragma unroll
        for (int reg = 0; reg < 4; ++reg) {
            int row = wm * 64 + sm * 16 + lhi * 4 + reg;
#pragma unroll
            for (int sn = 0; sn < 4; ++sn) {
                int col = wn * 64 + sn * 16 + llo;
                float v = fmaxf(acc[sm][sn][reg] + b1[col], 0.f);
                Afull[col >> 3][row][col & 7] = f2bfu(v);
            }
        }
    __syncthreads();

#pragma unroll
    for (int i = 0; i < 4; ++i)
#pragma unroll
        for (int j = 0; j < 4; ++j) acc[i][j] = (float4v){0.f, 0.f, 0.f, 0.f};

    // ---- phase 3: GEMM2 ----
    for (int kt = 0; kt < 4; ++kt) {
#pragma unroll
        for (int p = tid; p < 512; p += 256)
            *(uint4*)&Bst[0][0][p * 8] = W2v[kt * 512 + p];
        __syncthreads();
        short8v av[4], bv[4];
#pragma unroll
        for (int s = 0; s < 4; ++s) {
            av[s] = *(const short8v*)&Afull[kt * 4 + lhi][wm * 64 + s * 16 + llo][0];
            bv[s] = *(const short8v*)&Bst[lhi][wn * 64 + s * 16 + llo][0];
        }
#pragma unroll
        for (int sm = 0; sm < 4; ++sm)
#pragma unroll
            for (int sn = 0; sn < 4; ++sn)
                acc[sm][sn] = __builtin_amdgcn_mfma_f32_16x16x32_bf16(
                    av[sm], bv[sn], acc[sm][sn], 0, 0, 0);
        __syncthreads();
    }

    // ---- epilogue2: BN(eval)+relu -> global bf16 ----
#pragma unroll
    for (int sm = 0; sm < 4; ++sm)
#pragma unroll
        for (int reg = 0; reg < 4; ++reg) {
            int row = r0 + wm * 64 + sm * 16 + lhi * 4 + reg;
            if (row >= nrows) continue;
#pragma unroll
            for (int sn = 0; sn < 4; ++sn) {
                int col = wn * 64 + sn * 16 + llo;
                float v = acc[sm][sn][reg] + b2[col];
                v = v * (g[col] * BN_SCALE) + bb[col];
                v = fmaxf(v, 0.f);
                Cout[(size_t)row * 128 + col] = f2bfu(v);
            }
        }
}

// ================= global mean pool (bf16 in, fp32 out) =================
__device__ __forceinline__ int lower_bound_i(const int* a, int n, int v) {
    int lo = 0, hi = n;
    while (lo < hi) {
        int m = (lo + hi) >> 1;
        if (a[m] < v) lo = m + 1; else hi = m;
    }
    return lo;
}

__global__ __launch_bounds__(1024) void pool_kernel(const ushort* __restrict__ h,
                                                    const int* __restrict__ batch,
                                                    float* __restrict__ gf) {
    int b = blockIdx.x;
    int f = threadIdx.x & 127;
    int chunk = threadIdx.x >> 7;   // 0..7
    __shared__ float part[8][DH];
    int lo = lower_bound_i(batch, NN, b);
    int hi = lower_bound_i(batch, NN, b + 1);
    float sum = 0.f;
    for (int i = lo + chunk; i < hi; i += 8) sum += bf2f(h[(size_t)i * DH + f]);
    part[chunk][f] = sum;
    __syncthreads();
    if (chunk == 0) {
        float s = part[0][f] + part[1][f] + part[2][f] + part[3][f] +
                  part[4][f] + part[5][f] + part[6][f] + part[7][f];
        int cnt = hi - lo;
        gf[b * DH + f] = s / (float)(cnt > 0 ? cnt : 1);
    }
}

// ================= fusion + attention + classifier (fp32) =================
__global__ __launch_bounds__(1024) void fusion_kernel(
        const float* __restrict__ sem, const float* __restrict__ gf,
        const float* __restrict__ Ws, const float* __restrict__ bs,
        const float* __restrict__ Wg, const float* __restrict__ bg,
        const float* __restrict__ Wq, const float* __restrict__ Wk,
        const float* __restrict__ Wv,
        const float* __restrict__ Wc1, const float* __restrict__ bc1,
        const float* __restrict__ Wc2, const float* __restrict__ bc2,
        float* __restrict__ out) {
    int b = blockIdx.x;
    int tid = threadIdx.x;      // 1024
    int c = tid & 255;
    int kc = tid >> 8;          // 0..3
    __shared__ float tok[2][FD];
    __shared__ float part[4][FD];
    __shared__ float qv[6][FD]; // q0 q1 k0 k1 v0 v1
    __shared__ float att[4];
    __shared__ float fused[FD];
    __shared__ float c1s[FD / 2];

    {
        const float* sr = &sem[(size_t)b * SD];
        float acc = 0.f;
#pragma unroll 8
        for (int k = kc * 192; k < (kc + 1) * 192; ++k)
            acc = fmaf(sr[k], Ws[(size_t)k * FD + c], acc);
        part[kc][c] = acc;
    }
    __syncthreads();
    if (kc == 0)
        tok[0][c] = part[0][c] + part[1][c] + part[2][c] + part[3][c] + bs[c];
    __syncthreads();

    {
        const float* gr = &gf[(size_t)b * DH];
        float acc = 0.f;
#pragma unroll 8
        for (int k = kc * 32; k < (kc + 1) * 32; ++k)
            acc = fmaf(gr[k], Wg[(size_t)k * FD + c], acc);
        part[kc][c] = acc;
    }
    __syncthreads();
    if (kc == 0)
        tok[1][c] = part[0][c] + part[1][c] + part[2][c] + part[3][c] + bg[c];
    __syncthreads();

#pragma unroll
    for (int m = 0; m < 6; ++m) {
        const float* Wm = (m < 2) ? Wq : ((m < 4) ? Wk : Wv);
        int t = m & 1;
        float acc = 0.f;
#pragma unroll 8
        for (int k = kc * 64; k < (kc + 1) * 64; ++k)
            acc = fmaf(tok[t][k], Wm[(size_t)k * FD + c], acc);
        part[kc][c] = acc;
        __syncthreads();
        if (kc == 0)
            qv[m][c] = part[0][c] + part[1][c] + part[2][c] + part[3][c];
        __syncthreads();
    }

    if (tid < 256) {
        int w = tid >> 6;
        int lane = tid & 63;
        int qi = w >> 1, ki = w & 1;
        float s = 0.f;
#pragma unroll
        for (int k = lane; k < FD; k += 64) s += qv[qi][k] * qv[2 + ki][k];
#pragma unroll
        for (int d = 1; d < 64; d <<= 1) s += __shfl_xor(s, d);
        if (lane == 0) att[w] = s * (1.0f / 16.0f);
    }
    __syncthreads();
    if (tid < 2) {
        float a0 = att[tid * 2], a1 = att[tid * 2 + 1];
        float mx = fmaxf(a0, a1);
        float e0 = __expf(a0 - mx), e1 = __expf(a1 - mx);
        float inv = 1.f / (e0 + e1);
        att[tid * 2] = e0 * inv;
        att[tid * 2 + 1] = e1 * inv;
    }
    __syncthreads();

    if (kc == 0)
        fused[c] = 0.5f * ((att[0] + att[2]) * qv[4][c] + (att[1] + att[3]) * qv[5][c]);
    __syncthreads();

    {
        float* pf = &part[0][0];   // flat [1024]
        int cc = tid & 127;
        int k2 = tid >> 7;          // 0..7
        float acc = 0.f;
#pragma unroll 8
        for (int k = k2 * 32; k < (k2 + 1) * 32; ++k)
            acc = fmaf(fused[k], Wc1[(size_t)k * (FD / 2) + cc], acc);
        pf[tid] = acc;
        __syncthreads();
        if (tid < 128) {
            float s = 0.f;
#pragma unroll
            for (int j = 0; j < 8; ++j) s += pf[j * 128 + tid];
            c1s[tid] = fmaxf(s + bc1[tid], 0.f);
        }
    }
    __syncthreads();

    if (tid < 128) {
        int w = tid >> 6;
        int lane = tid & 63;
        float s = c1s[lane] * Wc2[(size_t)lane * 2 + w] +
                  c1s[lane + 64] * Wc2[(size_t)(lane + 64) * 2 + w];
#pragma unroll
        for (int d = 1; d < 64; d <<= 1) s += __shfl_xor(s, d);
        if (lane == 0) out[b * 2 + w] = s + bc2[w];
    }
}

// ================= launch =================
extern "C" void kernel_launch(void* const* d_in, const int* in_sizes, int n_in,
                              void* d_out, int out_size, void* d_ws, size_t ws_size,
                              hipStream_t stream) {
    const float* sem   = (const float*)d_in[0];
    const float* x     = (const float*)d_in[1];
    const int*   ei    = (const int*)d_in[2];
    const int*   batch = (const int*)d_in[3];
    const int* src = ei;
    const int* dst = ei + NE;

    const float* c1W1 = (const float*)d_in[4];
    const float* c1b1 = (const float*)d_in[5];
    const float* c1W2 = (const float*)d_in[6];
    const float* c1b2 = (const float*)d_in[7];
    const float* c2W1 = (const float*)d_in[8];
    const float* c2b1 = (const float*)d_in[9];
    const float* c2W2 = (const float*)d_in[10];
    const float* c2b2 = (const float*)d_in[11];
    const float* c3W1 = (const float*)d_in[12];
    const float* c3b1 = (const float*)d_in[13];
    const float* c3W2 = (const float*)d_in[14];
    const float* c3b2 = (const float*)d_in[15];
    const float* bn1g = (const float*)d_in[16];
    const float* bn1b = (const float*)d_in[17];
    const float* bn2g = (const float*)d_in[18];
    const float* bn2b = (const float*)d_in[19];
    const float* bn3g = (const float*)d_in[20];
    const float* bn3b = (const float*)d_in[21];
    const float* Ws   = (const float*)d_in[22];
    const float* bs_  = (const float*)d_in[23];
    const float* Wg   = (const float*)d_in[24];
    const float* bg   = (const float*)d_in[25];
    const float* Wq   = (const float*)d_in[26];
    const float* Wk   = (const float*)d_in[27];
    const float* Wv   = (const float*)d_in[28];
    const float* Wc1  = (const float*)d_in[29];
    const float* bc1  = (const float*)d_in[30];
    const float* Wc2  = (const float*)d_in[31];
    const float* bc2  = (const float*)d_in[32];

    // workspace layout (bf16 intermediates)
    ushort* xb = (ushort*)d_ws;                   // [NN][128]
    ushort* P  = xb + (size_t)NN * DH;            // [NN][128]
    ushort* Q  = P + (size_t)NN * DH;             // [NN][128]
    ushort* R  = Q + (size_t)NN * DH;             // [NN][128]
    ushort* Wt = R + (size_t)NN * DH;             // 6 x 16384
    float* gf  = (float*)(Wt + 6 * 16384);        // [NB][128]
    int* counts  = (int*)(gf + (size_t)NB * DH);
    int* offsets = counts + NN;
    int* cursor  = offsets + NN;
    int* excl    = cursor + NN;
    int* bsums   = excl + NN;
    int* eidx    = bsums + 128;

    ushort* Wt1 = Wt;
    ushort* Wt2 = Wt + 16384;
    ushort* Wt3 = Wt + 2 * 16384;
    ushort* Wt4 = Wt + 3 * 16384;
    ushort* Wt5 = Wt + 4 * 16384;
    ushort* Wt6 = Wt + 5 * 16384;

    const int layer_grid = (NN + 127) / 128;
    const int cast_grid  = (NN + 3) / 4;
    const int edge_grid  = (NE + 255) / 256;

    // ---- CSR build (once per call, reused by all 3 layers) ----
    zero_counts<<<SCAN_NBLK, 1024, 0, stream>>>(counts);
    hist_kernel<<<edge_grid, 256, 0, stream>>>(dst, counts);
    scan1<<<SCAN_NBLK, 1024, 0, stream>>>(counts, excl, bsums);
    scan2<<<1, 128, 0, stream>>>(bsums, SCAN_NBLK);
    scan3<<<SCAN_NBLK, 1024, 0, stream>>>(excl, bsums, offsets, cursor);
    scatter8<<<2048, 256, 0, stream>>>(src, dst, cursor, eidx);

    // ---- input cast + weight prep ----
    xcast<<<cast_grid, 256, 0, stream>>>(x, xb);
    wprep6<<<48, 256, 0, stream>>>(c1W1, c1W2, c2W1, c2W2, c3W1, c3W2, Wt);

    // ---- fused GIN layers ----
    layer_fused<<<layer_grid, 256, 0, stream>>>(xb, offsets, counts, eidx,
                                                Wt1, c1b1, Wt2, c1b2, bn1g, bn1b, P, NN);
    layer_fused<<<layer_grid, 256, 0, stream>>>(P, offsets, counts, eidx,
                                                Wt3, c2b1, Wt4, c2b2, bn2g, bn2b, Q, NN);
    layer_fused<<<layer_grid, 256, 0, stream>>>(Q, offsets, counts, eidx,
                                                Wt5, c3b1, Wt6, c3b2, bn3g, bn3b, R, NN);

    // ---- pool + fusion ----
    pool_kernel<<<NB, 1024, 0, stream>>>(R, batch, gf);
    fusion_kernel<<<NB, 1024, 0, stream>>>(sem, gf, Ws, bs_, Wg, bg, Wq, Wk, Wv,
                                           Wc1, bc1, Wc2, bc2, (float*)d_out);
}

// Round 11
// 666.205 us; speedup vs baseline: 1.5600x; 1.5600x over previous
//
#include <hip/hip_runtime.h>
#include <hip/hip_bf16.h>

#define NN 100000
#define NE 1600000
#define NB 64
#define DIN 78
#define DH 128
#define SD 768
#define FD 256
#define SCAN_NBLK 98   // ceil(NN/1024)

// 1/sqrt(1 + 1e-5)
#define BN_SCALE 0.9999950000374997f

typedef __attribute__((ext_vector_type(8))) short short8v;
typedef __attribute__((ext_vector_type(8))) unsigned short ushort8v;
typedef __attribute__((ext_vector_type(4))) float float4v;

__device__ __forceinline__ float bf2f(ushort u) {
    return __uint_as_float(((unsigned int)u) << 16);
}
__device__ __forceinline__ ushort f2bfu(float f) {
    __hip_bfloat16 h = __float2bfloat16(f);
    ushort u;
    __builtin_memcpy(&u, &h, 2);
    return u;
}

// ================= CSR build =================
__global__ void zero_counts(int* __restrict__ counts) {
    int i = blockIdx.x * 1024 + threadIdx.x;
    if (i < NN) counts[i] = 0;
}

__global__ void hist_kernel(const int* __restrict__ dst, int* __restrict__ counts) {
    int e = blockIdx.x * 256 + threadIdx.x;
    if (e < NE) atomicAdd(&counts[dst[e]], 1);
}

__global__ __launch_bounds__(1024) void scan1(const int* __restrict__ counts,
                                              int* __restrict__ excl,
                                              int* __restrict__ bsums) {
    __shared__ int tmp[1024];
    int tid = threadIdx.x;
    int i = blockIdx.x * 1024 + tid;
    int v = (i < NN) ? counts[i] : 0;
    tmp[tid] = v;
    __syncthreads();
#pragma unroll
    for (int off = 1; off < 1024; off <<= 1) {
        int t = (tid >= off) ? tmp[tid - off] : 0;
        __syncthreads();
        tmp[tid] += t;
        __syncthreads();
    }
    if (i < NN) excl[i] = tmp[tid] - v;
    if (tid == 1023) bsums[blockIdx.x] = tmp[1023];
}

__global__ __launch_bounds__(128) void scan2(int* __restrict__ bsums, int nb) {
    __shared__ int tmp[128];
    int tid = threadIdx.x;
    int v = (tid < nb) ? bsums[tid] : 0;
    tmp[tid] = v;
    __syncthreads();
#pragma unroll
    for (int off = 1; off < 128; off <<= 1) {
        int t = (tid >= off) ? tmp[tid - off] : 0;
        __syncthreads();
        tmp[tid] += t;
        __syncthreads();
    }
    if (tid < nb) bsums[tid] = tmp[tid] - v;
}

__global__ void scan3(const int* __restrict__ excl, const int* __restrict__ bsums,
                      int* __restrict__ offsets, int* __restrict__ cursor) {
    int i = blockIdx.x * 1024 + threadIdx.x;
    if (i < NN) {
        int v = excl[i] + bsums[blockIdx.x];
        offsets[i] = v;
        cursor[i] = v;
    }
}

// XCD-window scatter: blocks with the same (blockIdx.x & 7) land on the same
// XCD (round-robin dispatch); each XCD group owns one NN/8 dst window, so each
// eidx region is written by a single XCD -> full lines dirty in one L2.
__global__ __launch_bounds__(256) void scatter_xcd(const int* __restrict__ src,
                                                   const int* __restrict__ dst,
                                                   int* __restrict__ cursor,
                                                   int* __restrict__ eidx) {
    int xg = blockIdx.x & 7;
    int slot = blockIdx.x >> 3;           // 0..255 within group
    int base = slot * 256 + threadIdx.x;  // 0..65535
    const int stride = 256 * 256;
    int dlo = xg * (NN / 8);
    int dhi = (xg == 7) ? NN : (xg + 1) * (NN / 8);
#pragma unroll 1
    for (int e = base; e < NE; e += stride) {
        int d = dst[e];
        if (d >= dlo && d < dhi) {
            int q = atomicAdd(&cursor[d], 1);
            eidx[q] = src[e];
        }
    }
}

// ================= x -> bf16 padded [NN][128] =================
__global__ __launch_bounds__(256) void xcast(const float* __restrict__ x,
                                             ushort* __restrict__ xb) {
    int node = blockIdx.x * 4 + (threadIdx.x >> 6);
    if (node >= NN) return;
    int lane = threadIdx.x & 63;
    int col = lane * 2;
    ushort2 o = make_ushort2(0, 0);
    if (lane < 39) {
        float2 v = *(const float2*)&x[(size_t)node * DIN + col];
        o.x = f2bfu(v.x);
        o.y = f2bfu(v.y);
    }
    *(ushort2*)&xb[(size_t)node * DH + col] = o;
}

// ================= weight prep: all 6 weights in one launch =================
// Wt layout per weight: [kt(4)][kc(4)][col(128)][j(8)]  (kk = kt*32+kc*8+j)
__global__ __launch_bounds__(256) void wprep6(
        const float* __restrict__ W0, const float* __restrict__ W1,
        const float* __restrict__ W2, const float* __restrict__ W3,
        const float* __restrict__ W4, const float* __restrict__ W5,
        ushort* __restrict__ Wt) {
    int w = blockIdx.x >> 3;                    // 0..5
    const float* W = (w == 0) ? W0 : (w == 1) ? W1 : (w == 2) ? W2
                   : (w == 3) ? W3 : (w == 4) ? W4 : W5;
    int KW = (w == 0) ? DIN : DH;
    int t = (blockIdx.x & 7) * 256 + threadIdx.x;   // 0..2047
    int kt = t >> 9, kc = (t >> 7) & 3, col = t & 127;
    ushort tmp[8];
#pragma unroll
    for (int j = 0; j < 8; ++j) {
        int kk = kt * 32 + kc * 8 + j;
        tmp[j] = (kk < KW) ? f2bfu(W[(size_t)kk * 128 + col]) : (ushort)0;
    }
    *(uint4*)&Wt[(size_t)w * 16384 + (size_t)t * 8] = *(uint4*)&tmp[0];
}

// ================= gather aggregation (bf16 [NN][128]) =================
// z[n] = h[n] + sum_{neighbors}; quarter-wave (16 lanes x ushort8 = 16B) per
// neighbor row -> 4 rows in flight per wave; fp32 accumulate.
__global__ __launch_bounds__(256) void agg128(const ushort* __restrict__ h,
                                              const int* __restrict__ off,
                                              const int* __restrict__ cnt,
                                              const int* __restrict__ eidx,
                                              ushort* __restrict__ z) {
    int node = blockIdx.x * 4 + (threadIdx.x >> 6);
    if (node >= NN) return;
    int lane = threadIdx.x & 63;
    int q = lane >> 4;           // quarter-wave id: neighbor j % 4
    int llo = lane & 15;         // ushort8 index within row
    int start = off[node], deg = cnt[node];

    float acc[8];
#pragma unroll
    for (int i = 0; i < 8; ++i) acc[i] = 0.f;
    if (q == 0) {
        ushort8v v = *(const ushort8v*)&h[(size_t)node * DH + llo * 8];
#pragma unroll
        for (int i = 0; i < 8; ++i) acc[i] = bf2f(v[i]);
    }

    for (int base = 0; base < deg; base += 64) {
        int rem = deg - base;
        int m = rem < 64 ? rem : 64;
        int ev = (lane < m) ? eidx[start + base + lane] : 0;
#pragma unroll 4
        for (int j = q; j < m; j += 4) {
            int s = __shfl(ev, j);
            ushort8v v = *(const ushort8v*)&h[(size_t)s * DH + llo * 8];
#pragma unroll
            for (int i = 0; i < 8; ++i) acc[i] += bf2f(v[i]);
        }
    }

    // reduce across the 4 quarter-waves (lane bits 4 and 5)
#pragma unroll
    for (int i = 0; i < 8; ++i) {
        acc[i] += __shfl_xor(acc[i], 16);
        acc[i] += __shfl_xor(acc[i], 32);
    }
    if (q == 0) {
        ushort8v o;
#pragma unroll
        for (int i = 0; i < 8; ++i) o[i] = f2bfu(acc[i]);
        *(ushort8v*)&z[(size_t)node * DH + llo * 8] = o;
    }
}

// ================= fused GEMM pair =================
// R = relu((relu(A@Wt1+b1))@Wt2+b2)*g*BN_SCALE+bb), A bf16 [nrows][128].
// 128-row tile, 4 waves (2x2), 4x4 16x16 subtiles per wave, K=128 (4 steps).
// Intermediate kept in LDS (Afull); only R goes to HBM.
__global__ __launch_bounds__(256) void gemm12(
        const ushort* __restrict__ A,
        const ushort* __restrict__ Wt1, const float* __restrict__ b1,
        const ushort* __restrict__ Wt2, const float* __restrict__ b2,
        const float* __restrict__ g, const float* __restrict__ bb,
        ushort* __restrict__ Cout, int nrows) {
    __shared__ ushort Afull[16][129][8];   // [k-chunk][row(+pad)][j] 33 KB
    __shared__ ushort Bst[4][128][8];      // per-kt B stage, 8 KB
    const int tid = threadIdx.x;
    const int wave = tid >> 6, lane = tid & 63;
    const int wm = wave >> 1, wn = wave & 1;
    const int lhi = lane >> 4;             // 0..3
    const int llo = lane & 15;
    const int r0 = blockIdx.x * 128;

    // ---- stage A tile from global ----
#pragma unroll
    for (int p = tid; p < 2048; p += 256) {
        int row = p >> 4, chunk = p & 15;
        int grow = r0 + row;
        uint4 v = make_uint4(0u, 0u, 0u, 0u);
        if (grow < nrows)
            v = *(const uint4*)&A[(size_t)grow * DH + chunk * 8];
        *(uint4*)&Afull[chunk][row][0] = v;
    }
    __syncthreads();

    const uint4* W1v = (const uint4*)Wt1;
    const uint4* W2v = (const uint4*)Wt2;

    float4v acc[4][4];
#pragma unroll
    for (int i = 0; i < 4; ++i)
#pragma unroll
        for (int j = 0; j < 4; ++j) acc[i][j] = (float4v){0.f, 0.f, 0.f, 0.f};

    // ---- GEMM1 ----
    for (int kt = 0; kt < 4; ++kt) {
#pragma unroll
        for (int p = tid; p < 512; p += 256)
            *(uint4*)&Bst[0][0][p * 8] = W1v[kt * 512 + p];
        __syncthreads();
        short8v av[4], bv[4];
#pragma unroll
        for (int s = 0; s < 4; ++s) {
            av[s] = *(const short8v*)&Afull[kt * 4 + lhi][wm * 64 + s * 16 + llo][0];
            bv[s] = *(const short8v*)&Bst[lhi][wn * 64 + s * 16 + llo][0];
        }
#pragma unroll
        for (int sm = 0; sm < 4; ++sm)
#pragma unroll
            for (int sn = 0; sn < 4; ++sn)
                acc[sm][sn] = __builtin_amdgcn_mfma_f32_16x16x32_bf16(
                    av[sm], bv[sn], acc[sm][sn], 0, 0, 0);
        __syncthreads();
    }

    // ---- epilogue1: relu(+b1) -> Afull ----
#pragma unroll
    for (int sm = 0; sm < 4; ++sm)
#pragma unroll
        for (int reg = 0; reg < 4; ++reg) {
            int row = wm * 64 + sm * 16 + lhi * 4 + reg;
#pragma unroll
            for (int sn = 0; sn < 4; ++sn) {
                int col = wn * 64 + sn * 16 + llo;
                float v = fmaxf(acc[sm][sn][reg] + b1[col], 0.f);
                Afull[col >> 3][row][col & 7] = f2bfu(v);
            }
        }
    __syncthreads();

#pragma unroll
    for (int i = 0; i < 4; ++i)
#pragma unroll
        for (int j = 0; j < 4; ++j) acc[i][j] = (float4v){0.f, 0.f, 0.f, 0.f};

    // ---- GEMM2 ----
    for (int kt = 0; kt < 4; ++kt) {
#pragma unroll
        for (int p = tid; p < 512; p += 256)
            *(uint4*)&Bst[0][0][p * 8] = W2v[kt * 512 + p];
        __syncthreads();
        short8v av[4], bv[4];
#pragma unroll
        for (int s = 0; s < 4; ++s) {
            av[s] = *(const short8v*)&Afull[kt * 4 + lhi][wm * 64 + s * 16 + llo][0];
            bv[s] = *(const short8v*)&Bst[lhi][wn * 64 + s * 16 + llo][0];
        }
#pragma unroll
        for (int sm = 0; sm < 4; ++sm)
#pragma unroll
            for (int sn = 0; sn < 4; ++sn)
                acc[sm][sn] = __builtin_amdgcn_mfma_f32_16x16x32_bf16(
                    av[sm], bv[sn], acc[sm][sn], 0, 0, 0);
        __syncthreads();
    }

    // ---- epilogue2: BN(eval)+relu -> global bf16 ----
#pragma unroll
    for (int sm = 0; sm < 4; ++sm)
#pragma unroll
        for (int reg = 0; reg < 4; ++reg) {
            int row = r0 + wm * 64 + sm * 16 + lhi * 4 + reg;
            if (row >= nrows) continue;
#pragma unroll
            for (int sn = 0; sn < 4; ++sn) {
                int col = wn * 64 + sn * 16 + llo;
                float v = acc[sm][sn][reg] + b2[col];
                v = v * (g[col] * BN_SCALE) + bb[col];
                v = fmaxf(v, 0.f);
                Cout[(size_t)row * 128 + col] = f2bfu(v);
            }
        }
}

// ================= global mean pool (bf16 in, fp32 out) =================
__device__ __forceinline__ int lower_bound_i(const int* a, int n, int v) {
    int lo = 0, hi = n;
    while (lo < hi) {
        int m = (lo + hi) >> 1;
        if (a[m] < v) lo = m + 1; else hi = m;
    }
    return lo;
}

__global__ __launch_bounds__(1024) void pool_kernel(const ushort* __restrict__ h,
                                                    const int* __restrict__ batch,
                                                    float* __restrict__ gf) {
    int b = blockIdx.x;
    int f = threadIdx.x & 127;
    int chunk = threadIdx.x >> 7;   // 0..7
    __shared__ float part[8][DH];
    int lo = lower_bound_i(batch, NN, b);
    int hi = lower_bound_i(batch, NN, b + 1);
    float sum = 0.f;
    for (int i = lo + chunk; i < hi; i += 8) sum += bf2f(h[(size_t)i * DH + f]);
    part[chunk][f] = sum;
    __syncthreads();
    if (chunk == 0) {
        float s = part[0][f] + part[1][f] + part[2][f] + part[3][f] +
                  part[4][f] + part[5][f] + part[6][f] + part[7][f];
        int cnt = hi - lo;
        gf[b * DH + f] = s / (float)(cnt > 0 ? cnt : 1);
    }
}

// ================= fusion + attention + classifier (fp32) =================
__global__ __launch_bounds__(1024) void fusion_kernel(
        const float* __restrict__ sem, const float* __restrict__ gf,
        const float* __restrict__ Ws, const float* __restrict__ bs,
        const float* __restrict__ Wg, const float* __restrict__ bg,
        const float* __restrict__ Wq, const float* __restrict__ Wk,
        const float* __restrict__ Wv,
        const float* __restrict__ Wc1, const float* __restrict__ bc1,
        const float* __restrict__ Wc2, const float* __restrict__ bc2,
        float* __restrict__ out) {
    int b = blockIdx.x;
    int tid = threadIdx.x;      // 1024
    int c = tid & 255;
    int kc = tid >> 8;          // 0..3
    __shared__ float tok[2][FD];
    __shared__ float part[4][FD];
    __shared__ float qv[6][FD]; // q0 q1 k0 k1 v0 v1
    __shared__ float att[4];
    __shared__ float fused[FD];
    __shared__ float c1s[FD / 2];

    {
        const float* sr = &sem[(size_t)b * SD];
        float acc = 0.f;
#pragma unroll 8
        for (int k = kc * 192; k < (kc + 1) * 192; ++k)
            acc = fmaf(sr[k], Ws[(size_t)k * FD + c], acc);
        part[kc][c] = acc;
    }
    __syncthreads();
    if (kc == 0)
        tok[0][c] = part[0][c] + part[1][c] + part[2][c] + part[3][c] + bs[c];
    __syncthreads();

    {
        const float* gr = &gf[(size_t)b * DH];
        float acc = 0.f;
#pragma unroll 8
        for (int k = kc * 32; k < (kc + 1) * 32; ++k)
            acc = fmaf(gr[k], Wg[(size_t)k * FD + c], acc);
        part[kc][c] = acc;
    }
    __syncthreads();
    if (kc == 0)
        tok[1][c] = part[0][c] + part[1][c] + part[2][c] + part[3][c] + bg[c];
    __syncthreads();

#pragma unroll
    for (int m = 0; m < 6; ++m) {
        const float* Wm = (m < 2) ? Wq : ((m < 4) ? Wk : Wv);
        int t = m & 1;
        float acc = 0.f;
#pragma unroll 8
        for (int k = kc * 64; k < (kc + 1) * 64; ++k)
            acc = fmaf(tok[t][k], Wm[(size_t)k * FD + c], acc);
        part[kc][c] = acc;
        __syncthreads();
        if (kc == 0)
            qv[m][c] = part[0][c] + part[1][c] + part[2][c] + part[3][c];
        __syncthreads();
    }

    if (tid < 256) {
        int w = tid >> 6;
        int lane = tid & 63;
        int qi = w >> 1, ki = w & 1;
        float s = 0.f;
#pragma unroll
        for (int k = lane; k < FD; k += 64) s += qv[qi][k] * qv[2 + ki][k];
#pragma unroll
        for (int d = 1; d < 64; d <<= 1) s += __shfl_xor(s, d);
        if (lane == 0) att[w] = s * (1.0f / 16.0f);
    }
    __syncthreads();
    if (tid < 2) {
        float a0 = att[tid * 2], a1 = att[tid * 2 + 1];
        float mx = fmaxf(a0, a1);
        float e0 = __expf(a0 - mx), e1 = __expf(a1 - mx);
        float inv = 1.f / (e0 + e1);
        att[tid * 2] = e0 * inv;
        att[tid * 2 + 1] = e1 * inv;
    }
    __syncthreads();

    if (kc == 0)
        fused[c] = 0.5f * ((att[0] + att[2]) * qv[4][c] + (att[1] + att[3]) * qv[5][c]);
    __syncthreads();

    {
        float* pf = &part[0][0];   // flat [1024]
        int cc = tid & 127;
        int k2 = tid >> 7;          // 0..7
        float acc = 0.f;
#pragma unroll 8
        for (int k = k2 * 32; k < (k2 + 1) * 32; ++k)
            acc = fmaf(fused[k], Wc1[(size_t)k * (FD / 2) + cc], acc);
        pf[tid] = acc;
        __syncthreads();
        if (tid < 128) {
            float s = 0.f;
#pragma unroll
            for (int j = 0; j < 8; ++j) s += pf[j * 128 + tid];
            c1s[tid] = fmaxf(s + bc1[tid], 0.f);
        }
    }
    __syncthreads();

    if (tid < 128) {
        int w = tid >> 6;
        int lane = tid & 63;
        float s = c1s[lane] * Wc2[(size_t)lane * 2 + w] +
                  c1s[lane + 64] * Wc2[(size_t)(lane + 64) * 2 + w];
#pragma unroll
        for (int d = 1; d < 64; d <<= 1) s += __shfl_xor(s, d);
        if (lane == 0) out[b * 2 + w] = s + bc2[w];
    }
}

// ================= launch =================
extern "C" void kernel_launch(void* const* d_in, const int* in_sizes, int n_in,
                              void* d_out, int out_size, void* d_ws, size_t ws_size,
                              hipStream_t stream) {
    const float* sem   = (const float*)d_in[0];
    const float* x     = (const float*)d_in[1];
    const int*   ei    = (const int*)d_in[2];
    const int*   batch = (const int*)d_in[3];
    const int* src = ei;
    const int* dst = ei + NE;

    const float* c1W1 = (const float*)d_in[4];
    const float* c1b1 = (const float*)d_in[5];
    const float* c1W2 = (const float*)d_in[6];
    const float* c1b2 = (const float*)d_in[7];
    const float* c2W1 = (const float*)d_in[8];
    const float* c2b1 = (const float*)d_in[9];
    const float* c2W2 = (const float*)d_in[10];
    const float* c2b2 = (const float*)d_in[11];
    const float* c3W1 = (const float*)d_in[12];
    const float* c3b1 = (const float*)d_in[13];
    const float* c3W2 = (const float*)d_in[14];
    const float* c3b2 = (const float*)d_in[15];
    const float* bn1g = (const float*)d_in[16];
    const float* bn1b = (const float*)d_in[17];
    const float* bn2g = (const float*)d_in[18];
    const float* bn2b = (const float*)d_in[19];
    const float* bn3g = (const float*)d_in[20];
    const float* bn3b = (const float*)d_in[21];
    const float* Ws   = (const float*)d_in[22];
    const float* bs_  = (const float*)d_in[23];
    const float* Wg   = (const float*)d_in[24];
    const float* bg   = (const float*)d_in[25];
    const float* Wq   = (const float*)d_in[26];
    const float* Wk   = (const float*)d_in[27];
    const float* Wv   = (const float*)d_in[28];
    const float* Wc1  = (const float*)d_in[29];
    const float* bc1  = (const float*)d_in[30];
    const float* Wc2  = (const float*)d_in[31];
    const float* bc2  = (const float*)d_in[32];

    // workspace layout (bf16 intermediates)
    ushort* xb = (ushort*)d_ws;                   // [NN][128]
    ushort* P  = xb + (size_t)NN * DH;            // [NN][128]
    ushort* Q  = P + (size_t)NN * DH;             // [NN][128]
    ushort* R  = Q + (size_t)NN * DH;             // [NN][128]
    ushort* Wt = R + (size_t)NN * DH;             // 6 x 16384
    float* gf  = (float*)(Wt + 6 * 16384);        // [NB][128]
    int* counts  = (int*)(gf + (size_t)NB * DH);
    int* offsets = counts + NN;
    int* cursor  = offsets + NN;
    int* excl    = cursor + NN;
    int* bsums   = excl + NN;
    int* eidx    = bsums + 128;

    ushort* Wt1 = Wt;
    ushort* Wt2 = Wt + 16384;
    ushort* Wt3 = Wt + 2 * 16384;
    ushort* Wt4 = Wt + 3 * 16384;
    ushort* Wt5 = Wt + 4 * 16384;
    ushort* Wt6 = Wt + 5 * 16384;

    const int tile_grid = (NN + 127) / 128;
    const int cast_grid = (NN + 3) / 4;
    const int edge_grid = (NE + 255) / 256;

    // ---- CSR build (once per call, reused by all 3 layers) ----
    zero_counts<<<SCAN_NBLK, 1024, 0, stream>>>(counts);
    hist_kernel<<<edge_grid, 256, 0, stream>>>(dst, counts);
    scan1<<<SCAN_NBLK, 1024, 0, stream>>>(counts, excl, bsums);
    scan2<<<1, 128, 0, stream>>>(bsums, SCAN_NBLK);
    scan3<<<SCAN_NBLK, 1024, 0, stream>>>(excl, bsums, offsets, cursor);
    scatter_xcd<<<2048, 256, 0, stream>>>(src, dst, cursor, eidx);

    // ---- input cast + weight prep ----
    xcast<<<cast_grid, 256, 0, stream>>>(x, xb);
    wprep6<<<48, 256, 0, stream>>>(c1W1, c1W2, c2W1, c2W2, c3W1, c3W2, Wt);

    // ---- layer 1 ----
    agg128<<<cast_grid, 256, 0, stream>>>(xb, offsets, counts, eidx, P);
    gemm12<<<tile_grid, 256, 0, stream>>>(P, Wt1, c1b1, Wt2, c1b2, bn1g, bn1b, Q, NN);

    // ---- layer 2 ----
    agg128<<<cast_grid, 256, 0, stream>>>(Q, offsets, counts, eidx, P);
    gemm12<<<tile_grid, 256, 0, stream>>>(P, Wt3, c2b1, Wt4, c2b2, bn2g, bn2b, R, NN);

    // ---- layer 3 ----
    agg128<<<cast_grid, 256, 0, stream>>>(R, offsets, counts, eidx, P);
    gemm12<<<tile_grid, 256, 0, stream>>>(P, Wt5, c3b1, Wt6, c3b2, bn3g, bn3b, Q, NN);

    // ---- pool + fusion ----
    pool_kernel<<<NB, 1024, 0, stream>>>(Q, batch, gf);
    fusion_kernel<<<NB, 1024, 0, stream>>>(sem, gf, Ws, bs_, Wg, bg, Wq, Wk, Wv,
                                           Wc1, bc1, Wc2, bc2, (float*)d_out);
}